// Round 4
// baseline (176.933 us; speedup 1.0000x reference)
//
#include <hip/hip_runtime.h>
#include <math.h>

namespace {

constexpr int kB    = 16384;
constexpr int kS0   = 7;
constexpr int kS1   = 7;
constexpr int kD    = 30;
constexpr int kCells = kB * kS0 * kS1;   // 802816
constexpr int TPB   = 256;
constexpr int CPB   = 512;               // cells per block (2 tiles of 256)
constexpr int NBLK  = kCells / CPB;      // 1568 (exact)
constexpr float kInv7 = 1.0f / 7.0f;
constexpr float kWC = 5.0f;
constexpr float kWN = 0.5f;

__device__ __forceinline__ float sigm(float x) {
    return 1.0f / (1.0f + __expf(-x));
}

// Per-cell loss given the block's pred tile staged in LDS.
__device__ __forceinline__ float cell_loss(const float* __restrict__ sp, int tid,
                                           int cell, float4 tb4, int g, int tc)
{
    float f[kD];
    {
        const float2* p2 = reinterpret_cast<const float2*>(sp + tid * kD);
        #pragma unroll
        for (int q = 0; q < kD / 2; ++q) {
            float2 t = p2[q];
            f[2 * q]     = t.x;
            f[2 * q + 1] = t.y;
        }
    }

    const int cj = cell % kS1;            // column -> xg
    const int ci = (cell / kS1) % kS0;    // row    -> yg
    const float tox = tb4.x, toy = tb4.y, tw = tb4.z, th = tb4.w;

    const float conf0 = sigm(f[0]);
    const float conf1 = sigm(f[1]);
    float pbx[2], pby[2], pbw[2], pbh[2];
    #pragma unroll
    for (int k = 0; k < 2; ++k) {
        pbx[k] = sigm(f[2 + 4 * k + 0]);
        pby[k] = sigm(f[2 + 4 * k + 1]);
        pbw[k] = sigm(f[2 + 4 * k + 2]);
        pbh[k] = sigm(f[2 + 4 * k + 3]);
    }

    // softmax over 20 classes; only the value at tc is needed
    float cmax = f[10];
    #pragma unroll
    for (int q = 11; q < 30; ++q) cmax = fmaxf(cmax, f[q]);
    float csum = 0.0f, et = 0.0f;
    #pragma unroll
    for (int q = 0; q < 20; ++q) {
        const float e = __expf(f[10 + q] - cmax);
        csum += e;
        et = (q == tc) ? e : et;     // constant q -> cndmask
    }
    const float cls_t = et / csum;

    const float x = (float)cj, y = (float)ci;
    const float tcx = (x + tox) * kInv7;
    const float tcy = (y + toy) * kInv7;
    const float thw = tw * 0.5f, thh = th * 0.5f;
    const float tarea = tw * th;

    float iou[2];
    #pragma unroll
    for (int k = 0; k < 2; ++k) {
        const float pcx = (x + pbx[k]) * kInv7;
        const float pcy = (y + pby[k]) * kInv7;
        const float pw = pbw[k], ph = pbh[k];
        const float tb_ = fminf(tcx + thw, pcx + pw * 0.5f) - fmaxf(tcx - thw, pcx - pw * 0.5f);
        const float lr_ = fminf(tcy + thh, pcy + ph * 0.5f) - fmaxf(tcy - thh, pcy - ph * 0.5f);
        float inter = tb_ * lr_;
        inter = (tb_ < 0.0f || lr_ < 0.0f) ? 0.0f : inter;
        iou[k] = inter / (tarea + pw * ph - inter);
    }

    const bool b1 = (iou[1] > iou[0]);     // tie -> box 0 (first-max)
    const float bx = b1 ? pbx[1] : pbx[0];
    const float by = b1 ? pby[1] : pby[0];
    const float bw = b1 ? pbw[1] : pbw[0];
    const float bh = b1 ? pbh[1] : pbh[0];
    const float conf_b = b1 ? conf1 : conf0;
    const float iou_b  = b1 ? iou[1] : iou[0];

    const float dx = bx - tox;
    const float dy = by - toy;
    const float dw = sqrtf(bw) - sqrtf(tw);
    const float dh = sqrtf(bh) - sqrtf(th);
    const float coord = dx * dx + dy * dy + dw * dw + dh * dh;
    const float d1 = conf_b - iou_b;
    const float d2 = 1.0f - cls_t;
    const float obj   = kWC * coord + d1 * d1 + d2 * d2;
    const float noobj = kWN * (conf0 * conf0 + conf1 * conf1);

    return (g == 1) ? obj : noobj;
}

__global__ void __launch_bounds__(TPB) yolo_loss_kernel(
    const float* __restrict__ pred,
    const int*   __restrict__ grid,
    const float* __restrict__ tbox,
    const int*   __restrict__ tcls,
    float* __restrict__ out)
{
    __shared__ float sp[TPB * kD];        // 30720 B, reused for both tiles
    __shared__ float wsum[TPB / 64];

    const int tid  = threadIdx.x;
    const int base = blockIdx.x * CPB;
    const int wave = tid >> 6;
    const int lane = tid & 63;

    // --- issue ALL global loads up front (MLP ~19/thread):
    // 2 tiles x (7 + wave-uniform half) float4 pred loads + tbox/grid/tcls
    // for both cells. Tile-1 loads are still in flight while tile-0 computes.
    const float4* __restrict__ g4 =
        reinterpret_cast<const float4*>(pred + (size_t)base * kD);
    float4* s4 = reinterpret_cast<float4*>(sp);
    const bool extra = (tid < 128);       // waves 0,1 -> wave-uniform predicate

    float4 r0[7], r1[7], r0e, r1e;
    #pragma unroll
    for (int k = 0; k < 7; ++k) r0[k] = g4[tid + 256 * k];
    if (extra) r0e = g4[1792 + tid];
    #pragma unroll
    for (int k = 0; k < 7; ++k) r1[k] = g4[1920 + tid + 256 * k];
    if (extra) r1e = g4[1920 + 1792 + tid];

    const int cellA = base + tid;
    const int cellB = base + TPB + tid;
    const float4 tbA = reinterpret_cast<const float4*>(tbox)[cellA];
    const float4 tbB = reinterpret_cast<const float4*>(tbox)[cellB];
    const int gA = grid[cellA], gB = grid[cellB];
    const int tcA = tcls[cellA], tcB = tcls[cellB];

    // --- tile 0: stage, compute ---
    #pragma unroll
    for (int k = 0; k < 7; ++k) s4[tid + 256 * k] = r0[k];
    if (extra) s4[1792 + tid] = r0e;
    __syncthreads();
    float v = cell_loss(sp, tid, cellA, tbA, gA, tcA);
    __syncthreads();                      // protect LDS before overwrite

    // --- tile 1: stage (loads already landed / landing), compute ---
    #pragma unroll
    for (int k = 0; k < 7; ++k) s4[tid + 256 * k] = r1[k];
    if (extra) s4[1792 + tid] = r1e;
    __syncthreads();
    v += cell_loss(sp, tid, cellB, tbB, gB, tcB);

    // --- wave64 shuffle reduce, cross-wave via LDS, one atomic/block ---
    #pragma unroll
    for (int off = 32; off > 0; off >>= 1) v += __shfl_down(v, off, 64);
    if (lane == 0) wsum[wave] = v;
    __syncthreads();
    if (tid == 0) {
        atomicAdd(out, (wsum[0] + wsum[1] + wsum[2] + wsum[3]) * (1.0f / kB));
    }
}

} // namespace

extern "C" void kernel_launch(void* const* d_in, const int* in_sizes, int n_in,
                              void* d_out, int out_size, void* d_ws, size_t ws_size,
                              hipStream_t stream) {
    const float* pred = (const float*)d_in[0];
    const int*   grid = (const int*)d_in[1];
    const float* tbox = (const float*)d_in[2];
    const int*   tcls = (const int*)d_in[3];
    float* out = (float*)d_out;

    // d_out is re-poisoned (0xAA) before every timed replay -> zero it.
    // Memset node is cheaper than a kernel dispatch in graph replay.
    hipMemsetAsync(out, 0, sizeof(float), stream);
    yolo_loss_kernel<<<NBLK, TPB, 0, stream>>>(pred, grid, tbox, tcls, out);
}